// Round 7
// baseline (107.048 us; speedup 1.0000x reference)
//
#include <hip/hip_runtime.h>
#include <math.h>

#define B_      32
#define NP1     2001
#define D_      512
#define R_      6
#define NROLES  190
#define NVERBS  504
#define VOCAB   2001
#define NREG    2000

#define NSPL    16
#define K1CHUNK 128
#define PSTRIDE 3592        // 6*512 (SW) + 512 (rsum) + 8 (sumexp+pad)
#define PROW    2048        // padded P row
#define PSLICE  (192*PROW)  // 393216
#define NROLE_OUT (192*VOCAB)   // 384192
#define NB3B    1501        // ceil(NROLE_OUT/256)

// workspace layout (floats)
#define WS_U    8
#define WS_PART 1536
#define WS_AT   (1536 + B_*NSPL*PSTRIDE)     // A^T [512][192]
#define WS_P    (WS_AT + 512*192)            // 4 slices of [192][2048]

__device__ __forceinline__ float fast_tanh(float x) {
    float e = exp2f(x * 2.885390082f);
    return 1.0f - 2.0f * __builtin_amdgcn_rcpf(e + 1.0f);
}
__device__ __forceinline__ float fast_exp(float x) {
    return exp2f(x * 1.442695041f);
}

// 64-lane sum, all lanes get result. 4 DPP (VALU) + ds_swizzle + shfl.
__device__ __forceinline__ float wave_sum(float v) {
    int x;
    x = __builtin_amdgcn_update_dpp(0, __float_as_int(v), 0xB1, 0xF, 0xF, true);
    v += __int_as_float(x);
    x = __builtin_amdgcn_update_dpp(0, __float_as_int(v), 0x4E, 0xF, 0xF, true);
    v += __int_as_float(x);
    x = __builtin_amdgcn_update_dpp(0, __float_as_int(v), 0x124, 0xF, 0xF, true);
    v += __int_as_float(x);
    x = __builtin_amdgcn_update_dpp(0, __float_as_int(v), 0x128, 0xF, 0xF, true);
    v += __int_as_float(x);
    x = __builtin_amdgcn_ds_swizzle(__float_as_int(v), 0x401F);
    v += __int_as_float(x);
    v += __shfl_xor(v, 32, 64);
    return v;
}

// async global->LDS, 16B/lane; LDS dest = l + lane*16 (HW adds lane offset)
__device__ __forceinline__ void gload_lds16(const float* g, float* l) {
    __builtin_amdgcn_global_load_lds(
        (const __attribute__((address_space(1))) void*)g,
        (__attribute__((address_space(3))) void*)l, 16, 0, 0);
}

// ---------------- K0a: partial u[q][k] = sum_{d in q*64..} Wr[d][k]*Wa[d] ----------------
__global__ __launch_bounds__(256) void k0a_upart(
    const float* __restrict__ Wr, const float* __restrict__ Wa,
    float* __restrict__ ws_u) {
    const int q = blockIdx.x;
    const int k = threadIdx.x;
    if (k >= NROLES) return;
    float s = 0.f;
    const int d0 = q * 64;
    #pragma unroll 8
    for (int d = 0; d < 64; ++d)
        s += Wr[(size_t)(d0 + d) * NROLES + k] * Wa[d0 + d];
    ws_u[q * NROLES + k] = s;
}

// ---------------- K1: fused main pass; 512 blocks (2/CU exact); 3-pair ring ----------------
__global__ __launch_bounds__(256, 2) void k1_main(
    const float* __restrict__ vs, const float* __restrict__ Wa,
    const float* __restrict__ roles, const float* __restrict__ br,
    const float* __restrict__ ba, const float* __restrict__ ws_u,
    float* __restrict__ part) {
    const int b     = blockIdx.x >> 4;
    const int split = blockIdx.x & 15;
    const int tid   = threadIdx.x;
    const int lane  = tid & 63;
    const int w     = tid >> 6;

    __shared__ __align__(16) float smem[4 * 3600];   // ring (4*3072) then merge (4*3600)
    __shared__ float lse_[4][R_];
    float* ring = smem + w * 3072;

    const float4 wvA = *reinterpret_cast<const float4*>(Wa + D_ + lane * 4);
    const float4 wvB = *reinterpret_cast<const float4*>(Wa + D_ + 256 + lane * 4);

    const float* base = vs + (size_t)b * (NP1 * D_) + D_;
    const int n0 = split * K1CHUNK;
    const int nrows = min(n0 + K1CHUNK, NREG) - n0;  // 128 or 80
    const int cnt = nrows >> 2;                      // rows this wave (32 or 20)
    const int npairs = cnt >> 1;                     // 16 or 10

    // ---- stage first: get memory moving before the sr compute ----
    #pragma unroll
    for (int k = 0; k < 3; ++k) {
        const float* g0 = base + (size_t)(n0 + w + 8 * k) * D_ + lane * 4;
        float* s0 = ring + k * 1024;
        gload_lds16(g0, s0);
        gload_lds16(g0 + 256, s0 + 256);
        const float* g1 = g0 + 4 * D_;
        gload_lds16(g1, s0 + 512);
        gload_lds16(g1 + 256, s0 + 768);
    }
    asm volatile("" ::: "memory");   // keep sr loads after the ring issue

    // ---- inline s_role (L2-resident reads; overlaps ring latency) ----
    float sr[R_];
    {
        float pr[R_] = {0.f, 0.f, 0.f, 0.f, 0.f, 0.f};
        #pragma unroll
        for (int i = 0; i < 3; ++i) {
            const int k = lane + i * 64;
            if (k < NROLES) {
                float u = 0.f;
                #pragma unroll
                for (int q = 0; q < 8; ++q) u += ws_u[q * NROLES + k];
                #pragma unroll
                for (int r = 0; r < R_; ++r) pr[r] += roles[r * NROLES + k] * u;
            }
        }
        float c0 = 0.f;
        #pragma unroll
        for (int i = 0; i < 8; ++i) c0 += Wa[lane + i * 64] * br[lane + i * 64];
        c0 = wave_sum(c0) + ba[0];
        #pragma unroll
        for (int r = 0; r < R_; ++r) sr[r] = wave_sum(pr[r]) + c0;
    }

    float acc[R_][8];
    float rsum[8];
    float sume[R_];
    #pragma unroll
    for (int r = 0; r < R_; ++r) {
        sume[r] = 0.f;
        #pragma unroll
        for (int j = 0; j < 8; ++j) acc[r][j] = 0.f;
    }
    #pragma unroll
    for (int j = 0; j < 8; ++j) rsum[j] = 0.f;

    asm volatile("" ::: "memory");

    int st = 3;
    for (int p = 0; p < npairs; ++p) {
        const int rem = npairs - p;
        if (rem > 2)       asm volatile("s_waitcnt vmcnt(8)" ::: "memory");
        else if (rem == 2) asm volatile("s_waitcnt vmcnt(4)" ::: "memory");
        else               asm volatile("s_waitcnt vmcnt(0)" ::: "memory");

        const float* l0 = ring + (p % 3) * 1024;
        float4 x0A = *reinterpret_cast<const float4*>(l0 + lane * 4);
        float4 x0B = *reinterpret_cast<const float4*>(l0 + 256 + lane * 4);
        float4 x1A = *reinterpret_cast<const float4*>(l0 + 512 + lane * 4);
        float4 x1B = *reinterpret_cast<const float4*>(l0 + 768 + lane * 4);
        // consume (forces lgkm wait) BEFORE overwriting the slot
        float d0 = x0A.x*wvA.x + x0A.y*wvA.y + x0A.z*wvA.z + x0A.w*wvA.w
                 + x0B.x*wvB.x + x0B.y*wvB.y + x0B.z*wvB.z + x0B.w*wvB.w;
        float d1 = x1A.x*wvA.x + x1A.y*wvA.y + x1A.z*wvA.z + x1A.w*wvA.w
                 + x1B.x*wvB.x + x1B.y*wvB.y + x1B.z*wvB.z + x1B.w*wvB.w;
        if (st < npairs) {                 // refill the slot just consumed
            const float* g0 = base + (size_t)(n0 + w + 8 * st) * D_ + lane * 4;
            float* s0 = ring + (st % 3) * 1024;
            gload_lds16(g0, s0);
            gload_lds16(g0 + 256, s0 + 256);
            const float* g1 = g0 + 4 * D_;
            gload_lds16(g1, s0 + 512);
            gload_lds16(g1 + 256, s0 + 768);
            ++st;
        }
        d0 = wave_sum(d0);
        d1 = wave_sum(d1);
        float xs0[8] = {x0A.x,x0A.y,x0A.z,x0A.w,x0B.x,x0B.y,x0B.z,x0B.w};
        float xs1[8] = {x1A.x,x1A.y,x1A.z,x1A.w,x1B.x,x1B.y,x1B.z,x1B.w};
        #pragma unroll
        for (int r = 0; r < R_; ++r) {
            float t0 = fast_tanh(sr[r] + d0);
            float t1 = fast_tanh(sr[r] + d1);
            sume[r] += fast_exp(t0) + fast_exp(t1);
            #pragma unroll
            for (int j = 0; j < 8; ++j) acc[r][j] += t0 * xs0[j] + t1 * xs1[j];
        }
        #pragma unroll
        for (int j = 0; j < 8; ++j) rsum[j] += xs0[j] + xs1[j];
    }

    // ---- parallel merge: each wave dumps to its region, one barrier, sum ----
    __syncthreads();                      // ring no longer needed
    float* mine = smem + w * 3600;
    #pragma unroll
    for (int r = 0; r < R_; ++r) {
        *reinterpret_cast<float4*>(mine + r * 512 + lane * 4) =
            make_float4(acc[r][0], acc[r][1], acc[r][2], acc[r][3]);
        *reinterpret_cast<float4*>(mine + r * 512 + 256 + lane * 4) =
            make_float4(acc[r][4], acc[r][5], acc[r][6], acc[r][7]);
    }
    *reinterpret_cast<float4*>(mine + 6 * 512 + lane * 4) =
        make_float4(rsum[0], rsum[1], rsum[2], rsum[3]);
    *reinterpret_cast<float4*>(mine + 6 * 512 + 256 + lane * 4) =
        make_float4(rsum[4], rsum[5], rsum[6], rsum[7]);
    if (lane == 0) {
        #pragma unroll
        for (int r = 0; r < R_; ++r) lse_[w][r] = sume[r];
    }
    __syncthreads();
    float* dst = part + (size_t)(b * NSPL + split) * PSTRIDE;
    for (int i = tid; i < 896; i += 256) {
        float4 a0 = *reinterpret_cast<const float4*>(smem + 0 * 3600 + i * 4);
        float4 a1 = *reinterpret_cast<const float4*>(smem + 1 * 3600 + i * 4);
        float4 a2 = *reinterpret_cast<const float4*>(smem + 2 * 3600 + i * 4);
        float4 a3 = *reinterpret_cast<const float4*>(smem + 3 * 3600 + i * 4);
        reinterpret_cast<float4*>(dst)[i] = make_float4(
            a0.x + a1.x + a2.x + a3.x, a0.y + a1.y + a2.y + a3.y,
            a0.z + a1.z + a2.z + a3.z, a0.w + a1.w + a2.w + a3.w);
    }
    if (tid < R_)
        dst[3584 + tid] = lse_[0][tid] + lse_[1][tid] + lse_[2][tid] + lse_[3][tid];
}

// ---------------- K2: reduce partials -> relu(label_embed), write A^T ----------------
__global__ __launch_bounds__(256) void k2_reduce(
    const float* __restrict__ part, float* __restrict__ AT) {
    const int b = blockIdx.x;
    const int chunk = blockIdx.y;
    const int t = threadIdx.x;
    const int dl = t & 63;
    const int qg = t >> 6;
    const int d = chunk * 64 + dl;
    const float* pb = part + (size_t)b * NSPL * PSTRIDE;

    float s[7] = {0.f, 0.f, 0.f, 0.f, 0.f, 0.f, 0.f};
    for (int q = qg * 4; q < qg * 4 + 4; ++q) {
        const float* p = pb + (size_t)q * PSTRIDE;
        #pragma unroll
        for (int r = 0; r < R_; ++r) s[r] += p[r * D_ + d];
        s[6] += p[6 * D_ + d];
    }
    __shared__ float red[4][7][64];
    #pragma unroll
    for (int i = 0; i < 7; ++i) red[qg][i][dl] = s[i];
    __shared__ float lse_s[R_];
    if (t < R_) {
        float se = 0.f;
        for (int q = 0; q < NSPL; ++q) se += pb[(size_t)q * PSTRIDE + 3584 + t];
        lse_s[t] = logf(se);
    }
    __syncthreads();
    if (t < 64) {
        float rs = red[0][6][dl] + red[1][6][dl] + red[2][6][dl] + red[3][6][dl];
        #pragma unroll
        for (int r = 0; r < R_; ++r) {
            float sw = red[0][r][dl] + red[1][r][dl] + red[2][r][dl] + red[3][r][dl];
            // A^T[d][m] with m = b*6+r
            AT[(size_t)d * 192 + b * R_ + r] = fmaxf(sw - lse_s[r] * rs, 0.f);
        }
    }
}

// ---------------- K3: gemm partial; A from SGPR (A^T s_load), B via rotated LDS ----------------
// block: 32 m-rows (8/wave via SGPR) x 256 v (4/lane). grid (8 v, 6 m, 4 z).
__global__ __launch_bounds__(256) void k3_gemm(
    const float* __restrict__ AT, const float* __restrict__ Wl,
    float* __restrict__ P) {
    const int t    = threadIdx.x;
    const int lane = t & 63;
    const int w    = t >> 6;
    const int v0   = blockIdx.x * 256;
    const int m0   = blockIdx.y * 32;
    const int k0z  = blockIdx.z * 128;
    const int mb   = __builtin_amdgcn_readfirstlane(m0 + 8 * w);   // wave-uniform

    __shared__ __align__(16) float Bs[32][256];
    float acc[8][4];
    #pragma unroll
    for (int j = 0; j < 8; ++j)
        #pragma unroll
        for (int c = 0; c < 4; ++c) acc[j][c] = 0.f;

    for (int cch = 0; cch < 4; ++cch) {
        const int k0 = k0z + cch * 32;
        __syncthreads();
        // stage: Bs[k][granule ((v>>2)+k)&63, v&3] = Wl[v0+v][k0+k]
        #pragma unroll
        for (int i = 0; i < 8; ++i) {
            const int idx = t + i * 256;          // 0..2047
            const int v = idx >> 3;               // 0..255
            const int kq = (idx & 7) << 2;        // 0,4,..28
            float4 w4 = make_float4(0.f, 0.f, 0.f, 0.f);
            if (v0 + v < VOCAB)
                w4 = *reinterpret_cast<const float4*>(Wl + (size_t)(v0 + v) * D_ + k0 + kq);
            const int vg = v >> 2, vs = v & 3;
            Bs[kq + 0][(((vg + kq + 0) & 63) << 2) + vs] = w4.x;
            Bs[kq + 1][(((vg + kq + 1) & 63) << 2) + vs] = w4.y;
            Bs[kq + 2][(((vg + kq + 2) & 63) << 2) + vs] = w4.z;
            Bs[kq + 3][(((vg + kq + 3) & 63) << 2) + vs] = w4.w;
        }
        __syncthreads();
        const float* ATk = AT + (size_t)k0 * 192 + mb;
        #pragma unroll 8
        for (int k = 0; k < 32; ++k) {
            const float4 b4 = *reinterpret_cast<const float4*>(&Bs[k][((lane + k) & 63) << 2]);
            const float* a = ATk + k * 192;       // uniform -> s_load
            #pragma unroll
            for (int j = 0; j < 8; ++j) {
                const float aj = a[j];
                acc[j][0] += aj * b4.x;
                acc[j][1] += aj * b4.y;
                acc[j][2] += aj * b4.z;
                acc[j][3] += aj * b4.w;
            }
        }
    }
    float* Pz = P + (size_t)blockIdx.z * PSLICE;
    #pragma unroll
    for (int j = 0; j < 8; ++j) {
        // padded row (2048): unmasked aligned float4 store
        *reinterpret_cast<float4*>(Pz + (size_t)(mb + j) * PROW + v0 + lane * 4) =
            make_float4(acc[j][0], acc[j][1], acc[j][2], acc[j][3]);
    }
}

// ---------------- K_tail: {combine 4 gemm slices + bias} ∪ {verb head} ----------------
__global__ __launch_bounds__(256) void k_tail(
    const float* __restrict__ P, const float* __restrict__ bl,
    float* __restrict__ out_role,
    const float* __restrict__ vs, const float* __restrict__ Wv,
    const float* __restrict__ bv, float* __restrict__ out_verb) {
    const int bid = blockIdx.x;
    const int tid = threadIdx.x;
    if (bid < NB3B) {
        const int idx = bid * 256 + tid;
        if (idx < NROLE_OUT) {
            const int m = idx / VOCAB;
            const int v = idx - m * VOCAB;
            const size_t pi = (size_t)m * PROW + v;
            out_role[idx] = P[pi] + P[PSLICE + pi] + P[2 * PSLICE + pi]
                          + P[3 * PSLICE + pi] + bl[v];
        }
    } else {
        const int q = bid - NB3B;       // 0..63
        const int b = q >> 1;
        const int g = q & 1;
        __shared__ __align__(16) float a_s[D_];
        float2 x = reinterpret_cast<const float2*>(vs + (size_t)b * (NP1 * D_))[tid];
        reinterpret_cast<float2*>(a_s)[tid] = make_float2(fmaxf(x.x, 0.f), fmaxf(x.y, 0.f));
        __syncthreads();
        const int v = g * 252 + tid;
        if (tid < 252 && v < NVERBS) {
            const float* wrow = Wv + (size_t)v * D_;
            float s = 0.f;
            #pragma unroll 4
            for (int k = 0; k < D_; k += 4) {
                float4 w4 = *reinterpret_cast<const float4*>(wrow + k);
                s += a_s[k] * w4.x + a_s[k + 1] * w4.y + a_s[k + 2] * w4.z + a_s[k + 3] * w4.w;
            }
            out_verb[b * NVERBS + v] = s + bv[v];
        }
    }
}

extern "C" void kernel_launch(void* const* d_in, const int* in_sizes, int n_in,
                              void* d_out, int out_size, void* d_ws, size_t ws_size,
                              hipStream_t stream) {
    const float* vs    = (const float*)d_in[0];
    const float* roles = (const float*)d_in[1];
    const float* Wr    = (const float*)d_in[2];
    const float* br    = (const float*)d_in[3];
    const float* Wa    = (const float*)d_in[4];
    const float* ba    = (const float*)d_in[5];
    const float* Wv    = (const float*)d_in[6];
    const float* bv    = (const float*)d_in[7];
    const float* Wl    = (const float*)d_in[8];
    const float* bl    = (const float*)d_in[9];

    float* out_verb = (float*)d_out;
    float* out_role = (float*)d_out + B_ * NVERBS;
    float* ws       = (float*)d_ws;

    k0a_upart<<<dim3(8), dim3(256), 0, stream>>>(Wr, Wa, ws + WS_U);
    k1_main<<<dim3(B_ * NSPL), dim3(256), 0, stream>>>(vs, Wa, roles, br, ba,
                                                       ws + WS_U, ws + WS_PART);
    k2_reduce<<<dim3(B_, 8), dim3(256), 0, stream>>>(ws + WS_PART, ws + WS_AT);
    k3_gemm<<<dim3(8, 6, 4), dim3(256), 0, stream>>>(ws + WS_AT, Wl, ws + WS_P);
    k_tail<<<dim3(NB3B + 64), dim3(256), 0, stream>>>(ws + WS_P, bl, out_role,
                                                      vs, Wv, bv, out_verb);
}

// Round 8
// 79.848 us; speedup vs baseline: 1.3406x; 1.3406x over previous
//
#include <hip/hip_runtime.h>
#include <math.h>

#define B_      32
#define NP1     2001
#define D_      512
#define R_      6
#define NROLES  190
#define NVERBS  504
#define VOCAB   2001
#define NREG    2000

#define NSPLIT  32
#define CHUNK   64
#define PSTRIDE 3592        // 6*512 (SW) + 512 (rsum) + 8 (sumexp+pad)
// workspace layout (floats)
#define WS_U    8
#define WS_PART 1536
#define WS_A    (1536 + B_*NSPLIT*PSTRIDE)
#define WS_P    (WS_A + 192*D_)
#define PSZ     (192*VOCAB)
#define NB3B    1501        // ceil(PSZ/256)

__device__ __forceinline__ float fast_tanh(float x) {
    float e = exp2f(x * 2.885390082f);
    return 1.0f - 2.0f * __builtin_amdgcn_rcpf(e + 1.0f);
}
__device__ __forceinline__ float fast_exp(float x) {
    return exp2f(x * 1.442695041f);
}

// 64-lane sum, all lanes get result. 4 DPP (VALU) + ds_swizzle + shfl.
__device__ __forceinline__ float wave_sum(float v) {
    int x;
    x = __builtin_amdgcn_update_dpp(0, __float_as_int(v), 0xB1, 0xF, 0xF, true);
    v += __int_as_float(x);
    x = __builtin_amdgcn_update_dpp(0, __float_as_int(v), 0x4E, 0xF, 0xF, true);
    v += __int_as_float(x);
    x = __builtin_amdgcn_update_dpp(0, __float_as_int(v), 0x124, 0xF, 0xF, true);
    v += __int_as_float(x);
    x = __builtin_amdgcn_update_dpp(0, __float_as_int(v), 0x128, 0xF, 0xF, true);
    v += __int_as_float(x);
    x = __builtin_amdgcn_ds_swizzle(__float_as_int(v), 0x401F);
    v += __int_as_float(x);
    v += __shfl_xor(v, 32, 64);
    return v;
}

// async global->LDS, 16B/lane; LDS dest = l + lane*16 (HW adds lane offset)
__device__ __forceinline__ void gload_lds16(const float* g, float* l) {
    __builtin_amdgcn_global_load_lds(
        (const __attribute__((address_space(1))) void*)g,
        (__attribute__((address_space(3))) void*)l, 16, 0, 0);
}

// ---------------- K0a: partial u[q][k] = sum_{d in q*64..} Wr[d][k]*Wa[d] ----------------
__global__ __launch_bounds__(256) void k0a_upart(
    const float* __restrict__ Wr, const float* __restrict__ Wa,
    float* __restrict__ ws_u) {
    const int q = blockIdx.x;
    const int k = threadIdx.x;
    if (k >= NROLES) return;
    float s = 0.f;
    const int d0 = q * 64;
    #pragma unroll 8
    for (int d = 0; d < 64; ++d)
        s += Wr[(size_t)(d0 + d) * NROLES + k] * Wa[d0 + d];
    ws_u[q * NROLES + k] = s;
}

// ---------------- K1: fused main pass; inline s_role; 2-pair async LDS ring ----------------
// 32 KB LDS -> 4 blocks/CU (grid 1024 = exactly 4/CU, zero tail, 4 waves/SIMD)
__global__ __launch_bounds__(256, 4) void k1_main(
    const float* __restrict__ vs, const float* __restrict__ Wa,
    const float* __restrict__ roles, const float* __restrict__ br,
    const float* __restrict__ ba, const float* __restrict__ ws_u,
    float* __restrict__ part) {
    const int b     = blockIdx.x / NSPLIT;
    const int split = blockIdx.x % NSPLIT;
    const int tid   = threadIdx.x;
    const int lane  = tid & 63;
    const int w     = tid >> 6;

    __shared__ __align__(16) float smem[4 * 2 * 1024];   // 32 KB rings; reused for merge
    __shared__ float lse_[4][R_];
    float* ring = smem + w * 2048;

    const float4 wvA = *reinterpret_cast<const float4*>(Wa + D_ + lane * 4);
    const float4 wvB = *reinterpret_cast<const float4*>(Wa + D_ + 256 + lane * 4);

    const float* base = vs + (size_t)b * (NP1 * D_) + D_;
    const int n0 = split * CHUNK;
    const int nrows = min(n0 + CHUNK, NREG) - n0;    // 64 or 16
    const int cnt = (nrows - w + 3) >> 2;            // rows this wave (16 or 4)
    const int npairs = cnt >> 1;                     // 8 or 2

    // ---- stage first: get memory moving before the sr compute ----
    #pragma unroll
    for (int k = 0; k < 2; ++k) {
        const float* g0 = base + (size_t)(n0 + w + 8 * k) * D_ + lane * 4;
        float* s0 = ring + k * 1024;
        gload_lds16(g0, s0);
        gload_lds16(g0 + 256, s0 + 256);
        const float* g1 = g0 + 4 * D_;
        gload_lds16(g1, s0 + 512);
        gload_lds16(g1 + 256, s0 + 768);
    }
    asm volatile("" ::: "memory");

    // ---- inline s_role (L2-resident reads; overlaps ring latency) ----
    float sr[R_];
    {
        float pr[R_] = {0.f, 0.f, 0.f, 0.f, 0.f, 0.f};
        #pragma unroll
        for (int i = 0; i < 3; ++i) {
            const int k = lane + i * 64;
            if (k < NROLES) {
                float u = 0.f;
                #pragma unroll
                for (int q = 0; q < 8; ++q) u += ws_u[q * NROLES + k];
                #pragma unroll
                for (int r = 0; r < R_; ++r) pr[r] += roles[r * NROLES + k] * u;
            }
        }
        float c0 = 0.f;
        #pragma unroll
        for (int i = 0; i < 8; ++i) c0 += Wa[lane + i * 64] * br[lane + i * 64];
        c0 = wave_sum(c0) + ba[0];
        #pragma unroll
        for (int r = 0; r < R_; ++r) sr[r] = wave_sum(pr[r]) + c0;
    }

    float acc[R_][8];
    float rsum[8];
    float sume[R_];
    #pragma unroll
    for (int r = 0; r < R_; ++r) {
        sume[r] = 0.f;
        #pragma unroll
        for (int j = 0; j < 8; ++j) acc[r][j] = 0.f;
    }
    #pragma unroll
    for (int j = 0; j < 8; ++j) rsum[j] = 0.f;

    asm volatile("" ::: "memory");

    int st = 2;
    for (int p = 0; p < npairs; ++p) {
        const int rem = npairs - p;       // outstanding pairs = min(2, rem)
        if (rem > 1) asm volatile("s_waitcnt vmcnt(4)" ::: "memory");
        else         asm volatile("s_waitcnt vmcnt(0)" ::: "memory");

        const float* l0 = ring + (p & 1) * 1024;
        float4 x0A = *reinterpret_cast<const float4*>(l0 + lane * 4);
        float4 x0B = *reinterpret_cast<const float4*>(l0 + 256 + lane * 4);
        float4 x1A = *reinterpret_cast<const float4*>(l0 + 512 + lane * 4);
        float4 x1B = *reinterpret_cast<const float4*>(l0 + 768 + lane * 4);
        // consume (forces lgkm wait) BEFORE overwriting the slot
        float d0 = x0A.x*wvA.x + x0A.y*wvA.y + x0A.z*wvA.z + x0A.w*wvA.w
                 + x0B.x*wvB.x + x0B.y*wvB.y + x0B.z*wvB.z + x0B.w*wvB.w;
        float d1 = x1A.x*wvA.x + x1A.y*wvA.y + x1A.z*wvA.z + x1A.w*wvA.w
                 + x1B.x*wvB.x + x1B.y*wvB.y + x1B.z*wvB.z + x1B.w*wvB.w;
        if (st < npairs) {                 // refill the slot just consumed
            const float* g0 = base + (size_t)(n0 + w + 8 * st) * D_ + lane * 4;
            float* s0 = ring + (st & 1) * 1024;
            gload_lds16(g0, s0);
            gload_lds16(g0 + 256, s0 + 256);
            const float* g1 = g0 + 4 * D_;
            gload_lds16(g1, s0 + 512);
            gload_lds16(g1 + 256, s0 + 768);
            ++st;
        }
        d0 = wave_sum(d0);
        d1 = wave_sum(d1);
        float xs0[8] = {x0A.x,x0A.y,x0A.z,x0A.w,x0B.x,x0B.y,x0B.z,x0B.w};
        float xs1[8] = {x1A.x,x1A.y,x1A.z,x1A.w,x1B.x,x1B.y,x1B.z,x1B.w};
        #pragma unroll
        for (int r = 0; r < R_; ++r) {
            float t0 = fast_tanh(sr[r] + d0);
            float t1 = fast_tanh(sr[r] + d1);
            sume[r] += fast_exp(t0) + fast_exp(t1);
            #pragma unroll
            for (int j = 0; j < 8; ++j) acc[r][j] += t0 * xs0[j] + t1 * xs1[j];
        }
        #pragma unroll
        for (int j = 0; j < 8; ++j) rsum[j] += xs0[j] + xs1[j];
    }

    // merge the 4 waves into smem[0..3583] (reused -> barrier first)
    __syncthreads();
    float* ls = smem;
    for (int ww = 0; ww < 4; ++ww) {
        if (w == ww) {
            #pragma unroll
            for (int j = 0; j < 8; ++j) {
                const int dd = (j < 4) ? (lane * 4 + j) : (256 + lane * 4 + (j - 4));
                if (ww == 0) {
                    #pragma unroll
                    for (int r = 0; r < R_; ++r) ls[r * D_ + dd] = acc[r][j];
                    ls[6 * D_ + dd] = rsum[j];
                } else {
                    #pragma unroll
                    for (int r = 0; r < R_; ++r) ls[r * D_ + dd] += acc[r][j];
                    ls[6 * D_ + dd] += rsum[j];
                }
            }
            if (lane == 0) {
                #pragma unroll
                for (int r = 0; r < R_; ++r) lse_[ww][r] = sume[r];
            }
        }
        __syncthreads();
    }
    float* dst = part + (size_t)(b * NSPLIT + split) * PSTRIDE;
    for (int i = tid; i < 3584 / 4; i += 256)
        reinterpret_cast<float4*>(dst)[i] = reinterpret_cast<const float4*>(ls)[i];
    if (tid < R_)
        dst[3584 + tid] = lse_[0][tid] + lse_[1][tid] + lse_[2][tid] + lse_[3][tid];
}

// ---------------- K2: reduce partials -> relu(label_embed) ----------------
__global__ __launch_bounds__(256) void k2_reduce(
    const float* __restrict__ part, float* __restrict__ A) {
    const int b = blockIdx.x;
    const int chunk = blockIdx.y;
    const int t = threadIdx.x;
    const int dl = t & 63;
    const int qg = t >> 6;
    const int d = chunk * 64 + dl;
    const float* pb = part + (size_t)b * NSPLIT * PSTRIDE;

    float s[7] = {0.f, 0.f, 0.f, 0.f, 0.f, 0.f, 0.f};
    for (int q = qg * 8; q < qg * 8 + 8; ++q) {
        const float* p = pb + (size_t)q * PSTRIDE;
        #pragma unroll
        for (int r = 0; r < R_; ++r) s[r] += p[r * D_ + d];
        s[6] += p[6 * D_ + d];
    }
    __shared__ float red[4][7][64];
    #pragma unroll
    for (int i = 0; i < 7; ++i) red[qg][i][dl] = s[i];
    __shared__ float lse_s[R_];
    if (t < R_) {
        float se = 0.f;
        for (int q = 0; q < NSPLIT; ++q) se += pb[(size_t)q * PSTRIDE + 3584 + t];
        lse_s[t] = logf(se);
    }
    __syncthreads();
    if (t < 64) {
        float rs = red[0][6][dl] + red[1][6][dl] + red[2][6][dl] + red[3][6][dl];
        #pragma unroll
        for (int r = 0; r < R_; ++r) {
            float sw = red[0][r][dl] + red[1][r][dl] + red[2][r][dl] + red[3][r][dl];
            A[((size_t)b * R_ + r) * D_ + d] = fmaxf(sw - lse_s[r] * rs, 0.f);
        }
    }
}

// ---------------- K3: gemm partial, 64x64 tile, 4x4/thread, K split 2 ----------------
#define KC 64
__global__ __launch_bounds__(256) void k3_gemm(
    const float* __restrict__ A, const float* __restrict__ Wl,
    float* __restrict__ P) {
    const int t  = threadIdx.x;
    const int tx = t & 15;
    const int ty = t >> 4;
    const int v0 = blockIdx.x * 64;
    const int m0 = blockIdx.y * 64;
    const int kz = blockIdx.z * 256;
    __shared__ __align__(16) float As[KC][68];
    __shared__ __align__(16) float Bs[KC][68];
    float acc[4][4];
    #pragma unroll
    for (int i = 0; i < 4; ++i)
        #pragma unroll
        for (int c = 0; c < 4; ++c) acc[i][c] = 0.f;

    for (int cch = 0; cch < 4; ++cch) {
        const int k0 = kz + cch * KC;
        __syncthreads();
        #pragma unroll
        for (int i = 0; i < 4; ++i) {
            int idx = t + i * 256;
            int m = idx >> 4;
            int kq = (idx & 15) << 2;
            float4 a4 = *reinterpret_cast<const float4*>(A + (size_t)(m0 + m) * D_ + k0 + kq);
            As[kq + 0][m] = a4.x; As[kq + 1][m] = a4.y;
            As[kq + 2][m] = a4.z; As[kq + 3][m] = a4.w;
            float4 b4 = make_float4(0.f, 0.f, 0.f, 0.f);
            if (v0 + m < VOCAB)
                b4 = *reinterpret_cast<const float4*>(Wl + (size_t)(v0 + m) * D_ + k0 + kq);
            Bs[kq + 0][m] = b4.x; Bs[kq + 1][m] = b4.y;
            Bs[kq + 2][m] = b4.z; Bs[kq + 3][m] = b4.w;
        }
        __syncthreads();
        #pragma unroll 8
        for (int k = 0; k < KC; ++k) {
            float4 a4 = *reinterpret_cast<const float4*>(&As[k][ty * 4]);
            float4 b4 = *reinterpret_cast<const float4*>(&Bs[k][tx * 4]);
            float av[4] = {a4.x, a4.y, a4.z, a4.w};
            float bv[4] = {b4.x, b4.y, b4.z, b4.w};
            #pragma unroll
            for (int i = 0; i < 4; ++i)
                #pragma unroll
                for (int c = 0; c < 4; ++c) acc[i][c] += av[i] * bv[c];
        }
    }
    float* Pz = P + (size_t)blockIdx.z * PSZ;
    #pragma unroll
    for (int i = 0; i < 4; ++i) {
        int m = m0 + ty * 4 + i;
        #pragma unroll
        for (int c = 0; c < 4; ++c) {
            int v = v0 + tx * 4 + c;
            if (v < VOCAB) Pz[(size_t)m * VOCAB + v] = acc[i][c];
        }
    }
}

// ---------------- K_tail: {combine gemm halves + bias} ∪ {verb head} ----------------
__global__ __launch_bounds__(256) void k_tail(
    const float* __restrict__ P, const float* __restrict__ bl,
    float* __restrict__ out_role,
    const float* __restrict__ vs, const float* __restrict__ Wv,
    const float* __restrict__ bv, float* __restrict__ out_verb) {
    const int bid = blockIdx.x;
    const int tid = threadIdx.x;
    if (bid < NB3B) {
        const int idx = bid * 256 + tid;
        if (idx < PSZ) {
            const unsigned v = (unsigned)idx % VOCAB;
            out_role[idx] = P[idx] + P[PSZ + idx] + bl[v];
        }
    } else {
        const int q = bid - NB3B;       // 0..63
        const int b = q >> 1;
        const int g = q & 1;
        __shared__ __align__(16) float a_s[D_];
        float2 x = reinterpret_cast<const float2*>(vs + (size_t)b * (NP1 * D_))[tid];
        reinterpret_cast<float2*>(a_s)[tid] = make_float2(fmaxf(x.x, 0.f), fmaxf(x.y, 0.f));
        __syncthreads();
        const int v = g * 252 + tid;
        if (tid < 252 && v < NVERBS) {
            const float* wrow = Wv + (size_t)v * D_;
            float s = 0.f;
            #pragma unroll 4
            for (int k = 0; k < D_; k += 4) {
                float4 w4 = *reinterpret_cast<const float4*>(wrow + k);
                s += a_s[k] * w4.x + a_s[k + 1] * w4.y + a_s[k + 2] * w4.z + a_s[k + 3] * w4.w;
            }
            out_verb[b * NVERBS + v] = s + bv[v];
        }
    }
}

extern "C" void kernel_launch(void* const* d_in, const int* in_sizes, int n_in,
                              void* d_out, int out_size, void* d_ws, size_t ws_size,
                              hipStream_t stream) {
    const float* vs    = (const float*)d_in[0];
    const float* roles = (const float*)d_in[1];
    const float* Wr    = (const float*)d_in[2];
    const float* br    = (const float*)d_in[3];
    const float* Wa    = (const float*)d_in[4];
    const float* ba    = (const float*)d_in[5];
    const float* Wv    = (const float*)d_in[6];
    const float* bv    = (const float*)d_in[7];
    const float* Wl    = (const float*)d_in[8];
    const float* bl    = (const float*)d_in[9];

    float* out_verb = (float*)d_out;
    float* out_role = (float*)d_out + B_ * NVERBS;
    float* ws       = (float*)d_ws;

    k0a_upart<<<dim3(8), dim3(256), 0, stream>>>(Wr, Wa, ws + WS_U);
    k1_main<<<dim3(B_ * NSPLIT), dim3(256), 0, stream>>>(vs, Wa, roles, br, ba,
                                                         ws + WS_U, ws + WS_PART);
    k2_reduce<<<dim3(B_, 8), dim3(256), 0, stream>>>(ws + WS_PART, ws + WS_A);
    k3_gemm<<<dim3(32, 3, 2), dim3(256), 0, stream>>>(ws + WS_A, Wl, ws + WS_P);
    k_tail<<<dim3(NB3B + 64), dim3(256), 0, stream>>>(ws + WS_P, bl, out_role,
                                                      vs, Wv, bv, out_verb);
}